// Round 5
// baseline (386.158 us; speedup 1.0000x reference)
//
#include <hip/hip_runtime.h>
#include <math.h>

// DNC MemoryAccess forward. B=8, T=16, N=512, W=64, R=4, NW=1, MODES=3, IFACE=471.
// Persistent kernel: 128 blocks (16/batch) x 1024 threads (4 waves/SIMD latency hiding).
// L + LT + Mem shards in LDS; usage/prec/ww replicated per block. ONE relaxed flag-barrier
// per step; cross-block data via relaxed agent-scope atomics. wc-dots & alloc for t+1
// published during step t; read_words 2-deep pipeline; iface parse for t+1 runs between
// publish and barrier to hide the drain.

#define NBATCH 8
#define GPB    16
#define NBLK   (NBATCH*GPB)
#define BS     1024
#define NROW   32
#define NTT    16
#define NSLOT  512
#define WRD    64
#define RH     4
#define NIF    471
#define LSTR   520
#define MSTR   65
#define EPSV   1e-6f

// per-parity per-batch float offsets in exchange region
#define B_ALO  0            // [512] allocation
#define B_WDT  512          // [512] write-content raw dots
#define B_MNR  1024         // [512] memory row norms
#define B_ER   1536         // [4][512] read-content exp
#define B_SEP  3584         // [16][4] partial sums of ER
#define B_NN   3648         // [4][512] m0*bwd+m2*fwd
#define B_RWP  5696         // [16][256] read-word partials
#define BATF   9792
#define IFCF   (NBATCH*NTT*NIF)     // 60288 floats of iface
#define PARF   (NBATCH*BATF)

__device__ __forceinline__ float sigm(float x){ return 1.f/(1.f+expf(-x)); }
__device__ __forceinline__ float softpl(float x){ return x>0.f ? x+log1pf(expf(-x)) : log1pf(expf(x)); }
__device__ __forceinline__ float red32s(float v){ v+=__shfl_xor(v,1,32); v+=__shfl_xor(v,2,32); v+=__shfl_xor(v,4,32); v+=__shfl_xor(v,8,32); v+=__shfl_xor(v,16,32); return v; }
__device__ __forceinline__ float red32m(float v){ v*=__shfl_xor(v,1,32); v*=__shfl_xor(v,2,32); v*=__shfl_xor(v,4,32); v*=__shfl_xor(v,8,32); v*=__shfl_xor(v,16,32); return v; }
__device__ __forceinline__ float red64s(float v){
  v+=__shfl_xor(v,1); v+=__shfl_xor(v,2); v+=__shfl_xor(v,4);
  v+=__shfl_xor(v,8); v+=__shfl_xor(v,16); v+=__shfl_xor(v,32); return v; }

__device__ __forceinline__ void stg(float* p, float v){
  __hip_atomic_store(p, v, __ATOMIC_RELAXED, __HIP_MEMORY_SCOPE_AGENT);
}
__device__ __forceinline__ float ldc(const float* p){
  return __hip_atomic_load(p, __ATOMIC_RELAXED, __HIP_MEMORY_SCOPE_AGENT);
}

// flag slot: flg[b*256 + g*16] -- each block's flag in its own 64B line
__device__ __forceinline__ void lbar(unsigned* flg, int b, int g, unsigned gen, int tid){
  asm volatile("s_waitcnt vmcnt(0)" ::: "memory");
  __syncthreads();
  if (tid==0) __hip_atomic_store(flg+b*256+g*16, gen, __ATOMIC_RELAXED, __HIP_MEMORY_SCOPE_AGENT);
  if (tid<GPB){
    while (__hip_atomic_load(flg+b*256+tid*16, __ATOMIC_RELAXED, __HIP_MEMORY_SCOPE_AGENT) < gen)
      __builtin_amdgcn_s_sleep(1);
  }
  __syncthreads();
  asm volatile("" ::: "memory");
}

__global__ void __launch_bounds__(BS)
dnc_kernel(const float* __restrict__ ctrl, const float* __restrict__ wif,
           const float* __restrict__ bif, const float* __restrict__ mem0,
           float* __restrict__ out, float* __restrict__ ws, unsigned* __restrict__ flg)
{
  const int tid = threadIdx.x;
  const int bid = blockIdx.x;
  const int b   = bid & 7;
  const int g   = bid >> 3;
  const int n0  = g * NROW;

  __shared__ __align__(16) float L  [NROW*LSTR];
  __shared__ __align__(16) float LT [NROW*LSTR];
  __shared__ __align__(16) float Mem[NROW*MSTR];
  __shared__ __align__(16) float rwl[RH*NSLOT];
  __shared__ __align__(16) float wwl[NSLOT];
  __shared__ __align__(16) float usagel[NSLOT];
  __shared__ __align__(16) float precl[NSLOT];
  __shared__ __align__(16) float prs[480];
  __shared__ __align__(16) float aux[544];
  float* ern    = aux;        // [4][32]
  float* fwdb   = aux+128;    // [4][32]
  float* bwdb   = aux+256;    // [4][32]
  float* mnormo = aux+384;    // [32]
  float* modesA = aux+416;    // [2][12] parity-banked
  float* red    = aux+440;    // [32]
  float* wkst   = aux+472;    // [64]

  // ---------------- init ----------------
  for (int i=tid; i<NROW*LSTR; i+=BS){ L[i]=0.f; LT[i]=0.f; }
  for (int i=tid; i<NROW*WRD; i+=BS){
    int r=i>>6, k=i&63;
    Mem[r*MSTR+k] = mem0[(size_t)(b*NSLOT + n0 + r)*WRD + k];
  }
  if (tid<NSLOT){ usagel[tid]=0.f; precl[tid]=0.f; }
  { // iface GEMM: this block computes iface row (b, t=g); stage ctrl row in rwl
    float* ctrlrow = rwl;
    const float* crow = ctrl + (size_t)(b*NTT+g)*1024;
    for (int i=tid;i<1024;i+=BS) ctrlrow[i]=crow[i];
    __syncthreads();
    if (tid<NIF){
      int j=tid;
      float a0=0.f,a1=0.f,a2=0.f,a3=0.f;
      const float* wp = wif + j;
      for (int c=0;c<1024;c+=4){
        a0 += ctrlrow[c+0]*wp[(size_t)(c+0)*NIF];
        a1 += ctrlrow[c+1]*wp[(size_t)(c+1)*NIF];
        a2 += ctrlrow[c+2]*wp[(size_t)(c+2)*NIF];
        a3 += ctrlrow[c+3]*wp[(size_t)(c+3)*NIF];
      }
      ws[(size_t)(b*NTT+g)*NIF + j] = ((a0+a1)+(a2+a3)) + bif[j];
    }
  }
  __syncthreads();
  for (int i=tid;i<RH*NSLOT;i+=BS) rwl[i]=0.f;

  // heavy barrier (gen 1): makes plain-stored iface visible once
  __syncthreads();
  __builtin_amdgcn_fence(__ATOMIC_RELEASE, "agent");
  if (tid==0) __hip_atomic_store(flg+b*256+g*16, 1u, __ATOMIC_RELAXED, __HIP_MEMORY_SCOPE_AGENT);
  if (tid<GPB){
    while (__hip_atomic_load(flg+b*256+tid*16, __ATOMIC_RELAXED, __HIP_MEMORY_SCOPE_AGENT) < 1u)
      __builtin_amdgcn_s_sleep(1);
  }
  __syncthreads();
  __builtin_amdgcn_fence(__ATOMIC_ACQUIRE, "agent");

  // init publish (for step 0) into parity buffer 0
  {
    float* qb = ws + IFCF + 0*PARF + b*BATF;
    if (tid<64) wkst[tid] = ws[(size_t)(b*NTT+0)*NIF + 260 + tid];
    __syncthreads();
    { // wc dots + mnorm on mem0 shard (32 lanes/row, 2 elems each)
      int row=tid>>5, sub=tid&31;
      float wd=0.f, ms=0.f;
      #pragma unroll
      for (int j=0;j<2;j++){
        int k=sub*2+j; float m=Mem[row*MSTR+k];
        wd += m*wkst[k]; ms += m*m;
      }
      wd=red32s(wd); ms=red32s(ms);
      if (sub==0){ stg(qb+B_WDT+n0+row, wd); stg(qb+B_MNR+n0+row, sqrtf(ms)); }
    }
    { // alloc_0 shard
      int row=tid>>5, sub=tid&31, n=n0+row;
      float u_n=usagel[n], pr=1.f;
      for (int m=sub;m<NSLOT;m+=32){
        float um=usagel[m];
        if (um<u_n || (um==u_n && m<n)) pr*=um;
      }
      pr=red32m(pr);
      if (sub==0) stg(qb+B_ALO+n, (1.f-u_n)*pr);
    }
  }
  // parse iface_0 into prs + modesA bank 0
  {
    const float* ifc = ws + (size_t)(b*NTT+0)*NIF;
    if (tid<NIF) prs[tid]=ifc[tid];
    __syncthreads();
    if (tid<4) prs[256+tid]=softpl(prs[256+tid]);
    else if (tid==4) prs[324]=softpl(prs[324]);
    else if (tid>=64 && tid<128) prs[325+(tid-64)]=sigm(prs[325+(tid-64)]);
    else if (tid>=128 && tid<132) prs[453+(tid-128)]=sigm(prs[453+(tid-128)]);
    else if (tid==132) prs[457]=sigm(prs[457]);
    else if (tid==133) prs[458]=sigm(prs[458]);
    else if (tid>=136 && tid<140){
      int r=tid-136;
      float x0=prs[459+r*3],x1=prs[460+r*3],x2=prs[461+r*3];
      float mx=fmaxf(x0,fmaxf(x1,x2));
      float e0=expf(x0-mx),e1=expf(x1-mx),e2=expf(x2-mx),s=e0+e1+e2;
      prs[459+r*3]=e0/s; prs[460+r*3]=e1/s; prs[461+r*3]=e2/s;
      modesA[r*3+0]=e0/s; modesA[r*3+1]=e1/s; modesA[r*3+2]=e2/s;
    }
    {
      int wv=tid>>6, lane=tid&63;
      if (wv<4){
        float v = (wv==0)? prs[260+lane] : prs[(wv-1)*64+lane];
        v = red64s(v*v);
        if (lane==0) prs[471+wv]=sqrtf(v);
        if (wv==0){
          float u=prs[192+lane];
          u=red64s(u*u);
          if (lane==0) prs[475]=sqrtf(u);
        }
      }
    }
  }
  lbar(flg, b, g, 2u, tid);

  // ---------------- time loop (t==NTT is the drain pseudo-step) ----------------
  for (int t=0; t<=NTT; t++){
    const float* pb = ws + IFCF + (t&1)*PARF + b*BATF;
    float*       qb = ws + IFCF + ((t+1)&1)*PARF + b*BATF;
    float* mprev = modesA + 12*((t+1)&1);   // modes of step t-1
    float* mcur  = modesA + 12*(t&1);       // modes of step t

    // ---- phase 1: assemble rw_{t-1}, read-word partials, drain out[t-2] ----
    if (t>0){
      float ev[2], nv[2];
      #pragma unroll
      for (int i=0;i<2;i++){ int idx=tid+BS*i; ev[i]=ldc(pb+B_ER+idx); nv[i]=ldc(pb+B_NN+idx); }
      if (tid<64){
        int gp=tid>>2, r=tid&3;
        float v=ldc(pb+B_SEP+gp*4+r);
        v+=__shfl_xor(v,4); v+=__shfl_xor(v,8); v+=__shfl_xor(v,16); v+=__shfl_xor(v,32);
        if (tid<4) red[tid]=v;   // Se[r]
      }
      __syncthreads();
      #pragma unroll
      for (int i=0;i<2;i++){
        int idx=tid+BS*i; int r=idx>>9;
        rwl[idx] = nv[i] + mprev[r*3+1]*ev[i]/red[r];
      }
      __syncthreads();
      if (tid<256){ // read-word partials for t-1 (Mem still = Mem_{t-1})
        int r=tid>>6, k=tid&63;
        float a=0.f;
        #pragma unroll
        for (int row=0;row<NROW;row++) a += rwl[r*NSLOT+n0+row]*Mem[row*MSTR+k];
        stg(qb+B_RWP+g*256+tid, a);
      }
      if (g==0 && t>=2 && tid<256){
        float s=0.f;
        for (int gp=0;gp<GPB;gp++) s+=ldc(pb+B_RWP+gp*256+tid);
        out[(size_t)(b*NTT+(t-2))*256+tid]=s;
      }
    }
    if (t==NTT) break;

    __syncthreads();

    // ---- phase 2b: write-content exp, Sw, ww ----
    {
      float al=0.f;
      if (tid<512){
        float wsv=prs[324], wkn=prs[471];
        float wd=ldc(pb+B_WDT+tid), mn=ldc(pb+B_MNR+tid);
        al=ldc(pb+B_ALO+tid);
        wwl[tid]=expf(wsv*wd/(wkn*mn+EPSV));
      }
      __syncthreads();
      if (tid<512){ float v=wwl[tid]; v=red64s(v); if ((tid&63)==0) red[4+(tid>>6)]=v; }
      __syncthreads();
      if (tid<512){
        const float Sw=red[4]+red[5]+red[6]+red[7]+red[8]+red[9]+red[10]+red[11];
        float agv=prs[457], wgv=prs[458];
        wwl[tid]=wgv*(agv*al+(1.f-agv)*wwl[tid]/Sw);
      }
    }
    __syncthreads();

    // ---- S1: Sww partials, merged L/LT update (prec old), usage update ----
    if (tid<512){ float v=wwl[tid]; v=red64s(v); if ((tid&63)==0) red[12+(tid>>6)]=v; }
    #pragma unroll
    for (int i=0;i<4;i++){
      int e=tid+BS*i, row=e>>7, mb=(e&127)*4;
      float wn=wwl[n0+row];
      float pmn=precl[n0+row];
      float4 wm=*(float4*)&wwl[mb];
      float4 pm=*(float4*)&precl[mb];
      float c0=1.f-wn-wm.x, c1=1.f-wn-wm.y, c2=1.f-wn-wm.z, c3=1.f-wn-wm.w;
      float4 l4=*(float4*)&L[row*LSTR+mb];
      l4.x=c0*l4.x+wn*pm.x; l4.y=c1*l4.y+wn*pm.y;
      l4.z=c2*l4.z+wn*pm.z; l4.w=c3*l4.w+wn*pm.w;
      float4 t4=*(float4*)&LT[row*LSTR+mb];
      t4.x=c0*t4.x+wm.x*pmn; t4.y=c1*t4.y+wm.y*pmn;
      t4.z=c2*t4.z+wm.z*pmn; t4.w=c3*t4.w+wm.w*pmn;
      int d=(n0+row)-mb;
      if (d>=0 && d<4){ ((float*)&l4)[d]=0.f; ((float*)&t4)[d]=0.f; }
      *(float4*)&L[row*LSTR+mb]=l4;
      *(float4*)&LT[row*LSTR+mb]=t4;
    }
    if (tid<512){
      float wn=wwl[tid];
      float psi=(1.f-prs[453]*rwl[tid])*(1.f-prs[454]*rwl[NSLOT+tid])
               *(1.f-prs[455]*rwl[2*NSLOT+tid])*(1.f-prs[456]*rwl[3*NSLOT+tid]);
      usagel[tid]=(usagel[tid]+wn-usagel[tid]*wn)*psi;
    }
    __syncthreads();

    // ---- S2: prec update, wk_{t+1} stage, Mem update + read-content dots, fwd/bwd ----
    if (tid<512){
      const float Sww=red[12]+red[13]+red[14]+red[15]+red[16]+red[17]+red[18]+red[19];
      precl[tid]=(1.f-Sww)*precl[tid]+wwl[tid];
    }
    if (t<NTT-1 && tid<64) wkst[tid] = ws[(size_t)(b*NTT+t+1)*NIF + 260 + tid];
    {
      int row=tid>>5, sub=tid&31;
      float wn=wwl[n0+row];
      float rd0=0.f,rd1=0.f,rd2=0.f,rd3=0.f,ms=0.f;
      #pragma unroll
      for (int j=0;j<2;j++){
        int k=sub*2+j;
        float m=Mem[row*MSTR+k];
        m = m*(1.f-wn*prs[325+k]) + wn*prs[389+k];
        Mem[row*MSTR+k]=m;
        rd0+=prs[  0+k]*m; rd1+=prs[ 64+k]*m; rd2+=prs[128+k]*m; rd3+=prs[192+k]*m;
        ms+=m*m;
      }
      rd0=red32s(rd0); rd1=red32s(rd1); rd2=red32s(rd2); rd3=red32s(rd3); ms=red32s(ms);
      if (sub==0){
        float mn=sqrtf(ms);
        ern[0*NROW+row]=expf(prs[256]*rd0/(prs[472]*mn+EPSV));
        ern[1*NROW+row]=expf(prs[257]*rd1/(prs[473]*mn+EPSV));
        ern[2*NROW+row]=expf(prs[258]*rd2/(prs[474]*mn+EPSV));
        ern[3*NROW+row]=expf(prs[259]*rd3/(prs[475]*mn+EPSV));
        mnormo[row]=mn;
      }
    }
    __syncthreads();   // Mem rows updated before fwd/bwd reads L-row f4 slices cleanly
    { // fwd[r][n own] = L_new[n]·rw ; bwd[r][m own] = LT_new[m]·rw (32 lanes/row)
      int row=tid>>5, sub=tid&31;
      const float* Lr = &L[row*LSTR];
      const float* Tr = &LT[row*LSTR];
      float fa0=0.f,fa1=0.f,fa2=0.f,fa3=0.f, ba0=0.f,ba1=0.f,ba2=0.f,ba3=0.f;
      #pragma unroll
      for (int jj=0;jj<4;jj++){
        int c4=(sub+32*jj)*4;
        float4 l4=*(const float4*)&Lr[c4];
        float4 t4=*(const float4*)&Tr[c4];
        float4 r0=*(const float4*)&rwl[0*NSLOT+c4];
        float4 r1=*(const float4*)&rwl[1*NSLOT+c4];
        float4 r2=*(const float4*)&rwl[2*NSLOT+c4];
        float4 r3=*(const float4*)&rwl[3*NSLOT+c4];
        fa0+=l4.x*r0.x+l4.y*r0.y+l4.z*r0.z+l4.w*r0.w;
        fa1+=l4.x*r1.x+l4.y*r1.y+l4.z*r1.z+l4.w*r1.w;
        fa2+=l4.x*r2.x+l4.y*r2.y+l4.z*r2.z+l4.w*r2.w;
        fa3+=l4.x*r3.x+l4.y*r3.y+l4.z*r3.z+l4.w*r3.w;
        ba0+=t4.x*r0.x+t4.y*r0.y+t4.z*r0.z+t4.w*r0.w;
        ba1+=t4.x*r1.x+t4.y*r1.y+t4.z*r1.z+t4.w*r1.w;
        ba2+=t4.x*r2.x+t4.y*r2.y+t4.z*r2.z+t4.w*r2.w;
        ba3+=t4.x*r3.x+t4.y*r3.y+t4.z*r3.z+t4.w*r3.w;
      }
      fa0=red32s(fa0); fa1=red32s(fa1); fa2=red32s(fa2); fa3=red32s(fa3);
      ba0=red32s(ba0); ba1=red32s(ba1); ba2=red32s(ba2); ba3=red32s(ba3);
      if (sub==0){
        fwdb[0*NROW+row]=fa0; fwdb[1*NROW+row]=fa1; fwdb[2*NROW+row]=fa2; fwdb[3*NROW+row]=fa3;
        bwdb[0*NROW+row]=ba0; bwdb[1*NROW+row]=ba1; bwdb[2*NROW+row]=ba2; bwdb[3*NROW+row]=ba3;
      }
    }
    __syncthreads();

    // ---- S4: publishes (NN/ER/SEP, MNR, alloc_{t+1}, wc-dots_{t+1}) ----
    if (tid<128){
      int r=tid>>5, row=tid&31;
      float e=ern[r*NROW+row];
      stg(qb+B_NN+r*NSLOT+n0+row, mcur[r*3+0]*bwdb[r*NROW+row] + mcur[r*3+2]*fwdb[r*NROW+row]);
      stg(qb+B_ER+r*NSLOT+n0+row, e);
      float v=e;
      v+=__shfl_xor(v,1,32); v+=__shfl_xor(v,2,32); v+=__shfl_xor(v,4,32);
      v+=__shfl_xor(v,8,32); v+=__shfl_xor(v,16,32);
      if (row==0) stg(qb+B_SEP+g*4+r, v);
    }
    if (tid<32) stg(qb+B_MNR+n0+tid, mnormo[tid]);
    {
      int row=tid>>5, sub=tid&31, n=n0+row;
      float u_n=usagel[n], pr=1.f;
      for (int m=sub;m<NSLOT;m+=32){
        float um=usagel[m];
        if (um<u_n || (um==u_n && m<n)) pr*=um;
      }
      pr=red32m(pr);
      if (sub==0) stg(qb+B_ALO+n, (1.f-u_n)*pr);
    }
    if (t<NTT-1){
      int row=tid>>5, sub=tid&31;
      float wd=0.f;
      #pragma unroll
      for (int j=0;j<2;j++){ int k=sub*2+j; wd += Mem[row*MSTR+k]*wkst[k]; }
      wd=red32s(wd);
      if (sub==0) stg(qb+B_WDT+n0+row, wd);
    }

    // ---- parse iface_{t+1} into prs + modesA bank (t+1)&1, hiding publish drain ----
    if (t<NTT-1){
      __syncthreads();   // all prs/modesA(old-bank-safe) uses of step t complete
      const float* ifc = ws + (size_t)(b*NTT+(t+1))*NIF;
      float* mnx = modesA + 12*((t+1)&1);
      if (tid<NIF) prs[tid]=ifc[tid];
      __syncthreads();
      if (tid<4) prs[256+tid]=softpl(prs[256+tid]);
      else if (tid==4) prs[324]=softpl(prs[324]);
      else if (tid>=64 && tid<128) prs[325+(tid-64)]=sigm(prs[325+(tid-64)]);
      else if (tid>=128 && tid<132) prs[453+(tid-128)]=sigm(prs[453+(tid-128)]);
      else if (tid==132) prs[457]=sigm(prs[457]);
      else if (tid==133) prs[458]=sigm(prs[458]);
      else if (tid>=136 && tid<140){
        int r=tid-136;
        float x0=prs[459+r*3],x1=prs[460+r*3],x2=prs[461+r*3];
        float mx=fmaxf(x0,fmaxf(x1,x2));
        float e0=expf(x0-mx),e1=expf(x1-mx),e2=expf(x2-mx),s=e0+e1+e2;
        prs[459+r*3]=e0/s; prs[460+r*3]=e1/s; prs[461+r*3]=e2/s;
        mnx[r*3+0]=e0/s; mnx[r*3+1]=e1/s; mnx[r*3+2]=e2/s;
      }
      {
        int wv=tid>>6, lane=tid&63;
        if (wv<4){
          float v = (wv==0)? prs[260+lane] : prs[(wv-1)*64+lane];
          v = red64s(v*v);
          if (lane==0) prs[471+wv]=sqrtf(v);
          if (wv==0){
            float u=prs[192+lane];
            u=red64s(u*u);
            if (lane==0) prs[475]=sqrtf(u);
          }
        }
      }
    }

    lbar(flg, b, g, 3u+(unsigned)t, tid);
  }

  // final barrier: partials_15 published during drain phase
  lbar(flg, b, g, 3u+NTT, tid);
  if (g==0 && tid<256){
    const float* fb = ws + IFCF + ((NTT+1)&1)*PARF + b*BATF;
    float s=0.f;
    for (int gp=0;gp<GPB;gp++) s+=ldc(fb+B_RWP+gp*256+tid);
    out[(size_t)(b*NTT+(NTT-1))*256+tid]=s;
  }
}

extern "C" void kernel_launch(void* const* d_in, const int* in_sizes, int n_in,
                              void* d_out, int out_size, void* d_ws, size_t ws_size,
                              hipStream_t stream)
{
  const float* ctrl=(const float*)d_in[0];
  const float* wif =(const float*)d_in[1];
  const float* bif =(const float*)d_in[2];
  const float* mem0=(const float*)d_in[3];
  float* outp=(float*)d_out;
  unsigned* flg=(unsigned*)d_ws;
  float* wsf=(float*)((char*)d_ws+8192);

  hipMemsetAsync(d_ws, 0, 8192, stream);   // zero generation flags each launch

  void* args[]={(void*)&ctrl,(void*)&wif,(void*)&bif,(void*)&mem0,(void*)&outp,(void*)&wsf,(void*)&flg};
  hipError_t err = hipLaunchCooperativeKernel((void*)dnc_kernel, dim3(NBLK), dim3(BS), args, 0, stream);
  if (err != hipSuccess){
    hipLaunchKernelGGL(dnc_kernel, dim3(NBLK), dim3(BS), 0, stream,
                       ctrl, wif, bif, mem0, outp, wsf, flg);
  }
}

// Round 6
// 378.668 us; speedup vs baseline: 1.0198x; 1.0198x over previous
//
#include <hip/hip_runtime.h>
#include <math.h>

// DNC MemoryAccess forward. B=8, T=16, N=512, W=64, R=4, NW=1, MODES=3, IFACE=471.
// Persistent kernel: 128 blocks (16/batch) x 512 threads. L + LT + Mem shards in LDS;
// usage/prec/ww replicated per block. ONE relaxed flag-barrier per step; all exchange
// loads issued in ONE burst at step top (packed 64-bit); 6 syncthreads per step.

#define NBATCH 8
#define GPB    16
#define NBLK   (NBATCH*GPB)
#define BS     512
#define NROW   32
#define NTT    16
#define NSLOT  512
#define WRD    64
#define RH     4
#define NIF    471
#define LSTR   520
#define MSTR   65
#define EPSV   1e-6f

// per-parity per-batch float offsets in exchange region
#define B_ALO  0            // [512] allocation
#define B_WM   512          // [512][2] (write-dot, mnorm) pairs
#define B_EN   1536         // [4*512][2] (read-content exp, m0*bwd+m2*fwd) pairs
#define B_SEP  5632         // [16][4] partial sums of ER
#define B_RWP  5696         // [16][256] read-word partials
#define BATF   9792
#define IFCF   (NBATCH*NTT*NIF)     // 60288 floats of iface
#define PARF   (NBATCH*BATF)

__device__ __forceinline__ float sigm(float x){ return 1.f/(1.f+expf(-x)); }
__device__ __forceinline__ float softpl(float x){ return x>0.f ? x+log1pf(expf(-x)) : log1pf(expf(x)); }
__device__ __forceinline__ float red16s(float v){ v+=__shfl_xor(v,1,16); v+=__shfl_xor(v,2,16); v+=__shfl_xor(v,4,16); v+=__shfl_xor(v,8,16); return v; }
__device__ __forceinline__ float red16m(float v){ v*=__shfl_xor(v,1,16); v*=__shfl_xor(v,2,16); v*=__shfl_xor(v,4,16); v*=__shfl_xor(v,8,16); return v; }
__device__ __forceinline__ float red64s(float v){
  v+=__shfl_xor(v,1); v+=__shfl_xor(v,2); v+=__shfl_xor(v,4);
  v+=__shfl_xor(v,8); v+=__shfl_xor(v,16); v+=__shfl_xor(v,32); return v; }

__device__ __forceinline__ void stg(float* p, float v){
  __hip_atomic_store(p, v, __ATOMIC_RELAXED, __HIP_MEMORY_SCOPE_AGENT);
}
__device__ __forceinline__ float ldc(const float* p){
  return __hip_atomic_load(p, __ATOMIC_RELAXED, __HIP_MEMORY_SCOPE_AGENT);
}
__device__ __forceinline__ void stg2(float* p, float x, float y){
  union { float2 f; unsigned long long u; } v; v.f=make_float2(x,y);
  __hip_atomic_store((unsigned long long*)p, v.u, __ATOMIC_RELAXED, __HIP_MEMORY_SCOPE_AGENT);
}
__device__ __forceinline__ float2 ldc2(const float* p){
  union { float2 f; unsigned long long u; } v;
  v.u=__hip_atomic_load((const unsigned long long*)p, __ATOMIC_RELAXED, __HIP_MEMORY_SCOPE_AGENT);
  return v.f;
}

// flag slot: flg[b*256 + g*16] -- each block's flag in its own 64B line
__device__ __forceinline__ void lbar(unsigned* flg, int b, int g, unsigned gen, int tid){
  asm volatile("s_waitcnt vmcnt(0)" ::: "memory");
  __syncthreads();
  if (tid==0) __hip_atomic_store(flg+b*256+g*16, gen, __ATOMIC_RELAXED, __HIP_MEMORY_SCOPE_AGENT);
  if (tid<GPB){
    while (__hip_atomic_load(flg+b*256+tid*16, __ATOMIC_RELAXED, __HIP_MEMORY_SCOPE_AGENT) < gen)
      __builtin_amdgcn_s_sleep(1);
  }
  __syncthreads();
  asm volatile("" ::: "memory");
}

__global__ void __launch_bounds__(BS)
dnc_kernel(const float* __restrict__ ctrl, const float* __restrict__ wif,
           const float* __restrict__ bif, const float* __restrict__ mem0,
           float* __restrict__ out, float* __restrict__ ws, unsigned* __restrict__ flg)
{
  const int tid = threadIdx.x;
  const int bid = blockIdx.x;
  const int b   = bid & 7;
  const int g   = bid >> 3;
  const int n0  = g * NROW;

  __shared__ __align__(16) float L  [NROW*LSTR];
  __shared__ __align__(16) float LT [NROW*LSTR];
  __shared__ __align__(16) float Mem[NROW*MSTR];
  __shared__ __align__(16) float rwl[RH*NSLOT];
  __shared__ __align__(16) float wwl[NSLOT];
  __shared__ __align__(16) float usagel[NSLOT];
  __shared__ __align__(16) float precl[NSLOT];
  __shared__ __align__(16) float prs[480];
  __shared__ __align__(16) float aux[472];
  float* ern    = aux;        // [4][32]
  float* fwdb   = aux+128;    // [4][32]
  float* bwdb   = aux+256;    // [4][32]
  float* mnormo = aux+384;    // [32]
  float* modesA = aux+416;    // [2][12] parity-banked
  float* red    = aux+440;    // [32]

  // ---------------- init ----------------
  for (int i=tid; i<NROW*LSTR; i+=BS){ L[i]=0.f; LT[i]=0.f; }
  for (int i=tid; i<NROW*WRD; i+=BS){
    int r=i>>6, k=i&63;
    Mem[r*MSTR+k] = mem0[(size_t)(b*NSLOT + n0 + r)*WRD + k];
  }
  if (tid<NSLOT){ usagel[tid]=0.f; precl[tid]=0.f; }
  { // iface GEMM: this block computes iface row (b, t=g); stage ctrl row in rwl
    float* ctrlrow = rwl;
    const float* crow = ctrl + (size_t)(b*NTT+g)*1024;
    for (int i=tid;i<1024;i+=BS) ctrlrow[i]=crow[i];
    __syncthreads();
    if (tid<NIF){
      int j=tid;
      float a0=0.f,a1=0.f,a2=0.f,a3=0.f;
      const float* wp = wif + j;
      for (int c=0;c<1024;c+=4){
        a0 += ctrlrow[c+0]*wp[(size_t)(c+0)*NIF];
        a1 += ctrlrow[c+1]*wp[(size_t)(c+1)*NIF];
        a2 += ctrlrow[c+2]*wp[(size_t)(c+2)*NIF];
        a3 += ctrlrow[c+3]*wp[(size_t)(c+3)*NIF];
      }
      ws[(size_t)(b*NTT+g)*NIF + j] = ((a0+a1)+(a2+a3)) + bif[j];
    }
  }
  __syncthreads();
  for (int i=tid;i<RH*NSLOT;i+=BS) rwl[i]=0.f;

  // heavy barrier (gen 1): makes plain-stored iface visible once
  __syncthreads();
  __builtin_amdgcn_fence(__ATOMIC_RELEASE, "agent");
  if (tid==0) __hip_atomic_store(flg+b*256+g*16, 1u, __ATOMIC_RELAXED, __HIP_MEMORY_SCOPE_AGENT);
  if (tid<GPB){
    while (__hip_atomic_load(flg+b*256+tid*16, __ATOMIC_RELAXED, __HIP_MEMORY_SCOPE_AGENT) < 1u)
      __builtin_amdgcn_s_sleep(1);
  }
  __syncthreads();
  __builtin_amdgcn_fence(__ATOMIC_ACQUIRE, "agent");

  // init publish (for step 0) into parity buffer 0
  {
    float* qb = ws + IFCF + 0*PARF + b*BATF;
    const float* ifc0 = ws + (size_t)(b*NTT+0)*NIF;
    { // wc dots + mnorm on mem0 shard (16 lanes/row, 4 elems each)
      int row=tid>>4, sub=tid&15;
      float wd=0.f, ms=0.f;
      #pragma unroll
      for (int j=0;j<4;j++){
        int k=sub*4+j; float m=Mem[row*MSTR+k];
        wd += m*ifc0[260+k]; ms += m*m;
      }
      wd=red16s(wd); ms=red16s(ms);
      if (sub==0) stg2(qb+B_WM+2*(n0+row), wd, sqrtf(ms));
    }
    { // alloc_0 shard
      int row=tid>>4, sub=tid&15, n=n0+row;
      float u_n=usagel[n], pr=1.f;
      for (int m=sub;m<NSLOT;m+=16){
        float um=usagel[m];
        if (um<u_n || (um==u_n && m<n)) pr*=um;
      }
      pr=red16m(pr);
      if (sub==0) stg(qb+B_ALO+n, (1.f-u_n)*pr);
    }
  }
  // parse iface_0 into prs + modesA bank 0
  {
    const float* ifc = ws + (size_t)(b*NTT+0)*NIF;
    if (tid<NIF) prs[tid]=ifc[tid];
    __syncthreads();
    if (tid<4) prs[256+tid]=softpl(prs[256+tid]);
    else if (tid==4) prs[324]=softpl(prs[324]);
    else if (tid>=64 && tid<128) prs[325+(tid-64)]=sigm(prs[325+(tid-64)]);
    else if (tid>=128 && tid<132) prs[453+(tid-128)]=sigm(prs[453+(tid-128)]);
    else if (tid==132) prs[457]=sigm(prs[457]);
    else if (tid==133) prs[458]=sigm(prs[458]);
    else if (tid>=136 && tid<140){
      int r=tid-136;
      float x0=prs[459+r*3],x1=prs[460+r*3],x2=prs[461+r*3];
      float mx=fmaxf(x0,fmaxf(x1,x2));
      float e0=expf(x0-mx),e1=expf(x1-mx),e2=expf(x2-mx),s=e0+e1+e2;
      prs[459+r*3]=e0/s; prs[460+r*3]=e1/s; prs[461+r*3]=e2/s;
      modesA[r*3+0]=e0/s; modesA[r*3+1]=e1/s; modesA[r*3+2]=e2/s;
    }
    {
      int wv=tid>>6, lane=tid&63;
      if (wv<4){
        float v = (wv==0)? prs[260+lane] : prs[(wv-1)*64+lane];
        v = red64s(v*v);
        if (lane==0) prs[471+wv]=sqrtf(v);
        if (wv==0){
          float u=prs[192+lane];
          u=red64s(u*u);
          if (lane==0) prs[475]=sqrtf(u);
        }
      }
    }
  }
  lbar(flg, b, g, 2u, tid);

  // ---------------- time loop (t==NTT is the drain pseudo-step) ----------------
  for (int t=0; t<=NTT; t++){
    const float* pb = ws + IFCF + (t&1)*PARF + b*BATF;
    float*       qb = ws + IFCF + ((t+1)&1)*PARF + b*BATF;
    float* mprev = modesA + 12*((t+1)&1);   // modes of step t-1
    float* mcur  = modesA + 12*(t&1);       // modes of step t

    // ---- burst: ALL exchange loads for this step, one round trip ----
    float2 en[4]; float sepv=0.f, rwpv=0.f; float2 wm=make_float2(0.f,1.f); float al=0.f;
    if (t>0){
      #pragma unroll
      for (int i=0;i<4;i++) en[i]=ldc2(pb+B_EN+2*(tid+BS*i));
      if (tid<64) sepv=ldc(pb+B_SEP+tid);
      if (t>=2 && tid<256) rwpv=ldc(pb+B_RWP+(tid&15)*256+g*16+(tid>>4));
    }
    if (t<NTT){
      wm=ldc2(pb+B_WM+2*tid);
      al=ldc(pb+B_ALO+tid);
    }

    // ---- A: ww-exp (regs), Se reduce ----
    float ewv=0.f;
    if (t<NTT){
      ewv=expf(prs[324]*wm.x/(prs[471]*wm.y+EPSV));
      wwl[tid]=ewv;
    }
    if (t>0 && tid<64){
      float v=sepv;
      v+=__shfl_xor(v,4); v+=__shfl_xor(v,8); v+=__shfl_xor(v,16); v+=__shfl_xor(v,32);
      if (tid<4) red[tid]=v;   // Se[r]
    }
    __syncthreads();                                   // sync 1

    // ---- B: rwl build, Sw partials ----
    if (t>0){
      #pragma unroll
      for (int i=0;i<4;i++){
        int idx=tid+BS*i; int r=idx>>9;
        rwl[idx] = en[i].y + mprev[r*3+1]*en[i].x/red[r];
      }
    }
    if (t<NTT){ float v=wwl[tid]; v=red64s(v); if ((tid&63)==0) red[4+(tid>>6)]=v; }
    __syncthreads();                                   // sync 2

    // ---- C: read-word partials (t-1), out drain (t-2), ww final ----
    if (t>0 && tid<256){
      int r=tid>>6, k=tid&63;
      float a=0.f;
      #pragma unroll
      for (int row=0;row<NROW;row++) a += rwl[r*NSLOT+n0+row]*Mem[row*MSTR+k];
      stg(qb+B_RWP+g*256+tid, a);
    }
    if (t>=2 && tid<256){
      float s=red16s(rwpv);    // sum over gp (16 consecutive lanes)
      if ((tid&15)==0) out[(size_t)(b*NTT+(t-2))*256 + g*16 + (tid>>4)] = s;
    }
    if (t==NTT) break;   // drain step done (publish flushed by final lbar)
    {
      const float Sw=red[4]+red[5]+red[6]+red[7]+red[8]+red[9]+red[10]+red[11];
      float agv=prs[457], wgv=prs[458];
      wwl[tid]=wgv*(agv*al+(1.f-agv)*ewv/Sw);
    }
    __syncthreads();                                   // sync 3

    // ---- D: Sww partials, merged L/LT update (prec old), usage update ----
    { float v=wwl[tid]; v=red64s(v); if ((tid&63)==0) red[12+(tid>>6)]=v; }
    #pragma unroll
    for (int i=0;i<8;i++){
      int e=tid+BS*i, row=e>>7, mb=(e&127)*4;
      float wn=wwl[n0+row];
      float pmn=precl[n0+row];
      float4 wmv=*(float4*)&wwl[mb];
      float4 pm=*(float4*)&precl[mb];
      float c0=1.f-wn-wmv.x, c1=1.f-wn-wmv.y, c2=1.f-wn-wmv.z, c3=1.f-wn-wmv.w;
      float4 l4=*(float4*)&L[row*LSTR+mb];
      l4.x=c0*l4.x+wn*pm.x; l4.y=c1*l4.y+wn*pm.y;
      l4.z=c2*l4.z+wn*pm.z; l4.w=c3*l4.w+wn*pm.w;
      float4 t4=*(float4*)&LT[row*LSTR+mb];
      t4.x=c0*t4.x+wmv.x*pmn; t4.y=c1*t4.y+wmv.y*pmn;
      t4.z=c2*t4.z+wmv.z*pmn; t4.w=c3*t4.w+wmv.w*pmn;
      int d=(n0+row)-mb;
      if (d>=0 && d<4){ ((float*)&l4)[d]=0.f; ((float*)&t4)[d]=0.f; }
      *(float4*)&L[row*LSTR+mb]=l4;
      *(float4*)&LT[row*LSTR+mb]=t4;
    }
    {
      float wn=wwl[tid];
      float psi=(1.f-prs[453]*rwl[tid])*(1.f-prs[454]*rwl[NSLOT+tid])
               *(1.f-prs[455]*rwl[2*NSLOT+tid])*(1.f-prs[456]*rwl[3*NSLOT+tid]);
      usagel[tid]=(usagel[tid]+wn-usagel[tid]*wn)*psi;
    }
    __syncthreads();                                   // sync 4

    // ---- E: prec update, Mem update + read-content dots, fwd/bwd ----
    {
      const float Sww=red[12]+red[13]+red[14]+red[15]+red[16]+red[17]+red[18]+red[19];
      precl[tid]=(1.f-Sww)*precl[tid]+wwl[tid];
    }
    {
      int row=tid>>4, sub=tid&15;
      float wn=wwl[n0+row];
      float rd0=0.f,rd1=0.f,rd2=0.f,rd3=0.f,ms=0.f;
      #pragma unroll
      for (int j=0;j<4;j++){
        int k=sub*4+j;
        float m=Mem[row*MSTR+k];
        m = m*(1.f-wn*prs[325+k]) + wn*prs[389+k];
        Mem[row*MSTR+k]=m;
        rd0+=prs[  0+k]*m; rd1+=prs[ 64+k]*m; rd2+=prs[128+k]*m; rd3+=prs[192+k]*m;
        ms+=m*m;
      }
      rd0=red16s(rd0); rd1=red16s(rd1); rd2=red16s(rd2); rd3=red16s(rd3); ms=red16s(ms);
      if (sub==0){
        float mn=sqrtf(ms);
        ern[0*NROW+row]=expf(prs[256]*rd0/(prs[472]*mn+EPSV));
        ern[1*NROW+row]=expf(prs[257]*rd1/(prs[473]*mn+EPSV));
        ern[2*NROW+row]=expf(prs[258]*rd2/(prs[474]*mn+EPSV));
        ern[3*NROW+row]=expf(prs[259]*rd3/(prs[475]*mn+EPSV));
        mnormo[row]=mn;
      }
    }
    { // fwd[r][n own] = L_new[n]·rw ; bwd[r][m own] = LT_new[m]·rw (16 lanes/row)
      int row=tid>>4, sub=tid&15;
      const float* Lr = &L[row*LSTR];
      const float* Tr = &LT[row*LSTR];
      float fa0=0.f,fa1=0.f,fa2=0.f,fa3=0.f, ba0=0.f,ba1=0.f,ba2=0.f,ba3=0.f;
      #pragma unroll
      for (int jj=0;jj<8;jj++){
        int c4=(sub+16*jj)*4;
        float4 l4=*(const float4*)&Lr[c4];
        float4 t4=*(const float4*)&Tr[c4];
        float4 r0=*(const float4*)&rwl[0*NSLOT+c4];
        float4 r1=*(const float4*)&rwl[1*NSLOT+c4];
        float4 r2=*(const float4*)&rwl[2*NSLOT+c4];
        float4 r3=*(const float4*)&rwl[3*NSLOT+c4];
        fa0+=l4.x*r0.x+l4.y*r0.y+l4.z*r0.z+l4.w*r0.w;
        fa1+=l4.x*r1.x+l4.y*r1.y+l4.z*r1.z+l4.w*r1.w;
        fa2+=l4.x*r2.x+l4.y*r2.y+l4.z*r2.z+l4.w*r2.w;
        fa3+=l4.x*r3.x+l4.y*r3.y+l4.z*r3.z+l4.w*r3.w;
        ba0+=t4.x*r0.x+t4.y*r0.y+t4.z*r0.z+t4.w*r0.w;
        ba1+=t4.x*r1.x+t4.y*r1.y+t4.z*r1.z+t4.w*r1.w;
        ba2+=t4.x*r2.x+t4.y*r2.y+t4.z*r2.z+t4.w*r2.w;
        ba3+=t4.x*r3.x+t4.y*r3.y+t4.z*r3.z+t4.w*r3.w;
      }
      fa0=red16s(fa0); fa1=red16s(fa1); fa2=red16s(fa2); fa3=red16s(fa3);
      ba0=red16s(ba0); ba1=red16s(ba1); ba2=red16s(ba2); ba3=red16s(ba3);
      if (sub==0){
        fwdb[0*NROW+row]=fa0; fwdb[1*NROW+row]=fa1; fwdb[2*NROW+row]=fa2; fwdb[3*NROW+row]=fa3;
        bwdb[0*NROW+row]=ba0; bwdb[1*NROW+row]=ba1; bwdb[2*NROW+row]=ba2; bwdb[3*NROW+row]=ba3;
      }
    }
    __syncthreads();                                   // sync 5

    // ---- F: publishes (EN/SEP, WM, ALO) ----
    if (tid<128){
      int r=tid>>5, row=tid&31;
      float e=ern[r*NROW+row];
      float nn=mcur[r*3+0]*bwdb[r*NROW+row] + mcur[r*3+2]*fwdb[r*NROW+row];
      stg2(qb+B_EN+2*(r*NSLOT+n0+row), e, nn);
      float v=e;
      v+=__shfl_xor(v,1,32); v+=__shfl_xor(v,2,32); v+=__shfl_xor(v,4,32);
      v+=__shfl_xor(v,8,32); v+=__shfl_xor(v,16,32);
      if (row==0) stg(qb+B_SEP+g*4+r, v);
    }
    {
      int row=tid>>4, sub=tid&15;
      float wd=0.f;
      if (t<NTT-1){
        const float* ifn = ws + (size_t)(b*NTT+(t+1))*NIF;
        #pragma unroll
        for (int j=0;j<4;j++){ int k=sub*4+j; wd += Mem[row*MSTR+k]*ifn[260+k]; }
        wd=red16s(wd);
      }
      if (sub==0) stg2(qb+B_WM+2*(n0+row), wd, mnormo[row]);
    }
    {
      int row=tid>>4, sub=tid&15, n=n0+row;
      float u_n=usagel[n], pr=1.f;
      for (int m=sub;m<NSLOT;m+=16){
        float um=usagel[m];
        if (um<u_n || (um==u_n && m<n)) pr*=um;
      }
      pr=red16m(pr);
      if (sub==0) stg(qb+B_ALO+n, (1.f-u_n)*pr);
    }

    // ---- parse iface_{t+1} into prs + modesA bank (t+1)&1 (hides publish drain) ----
    if (t<NTT-1){
      __syncthreads();                                 // sync 6 (prs reuse)
      const float* ifc = ws + (size_t)(b*NTT+(t+1))*NIF;
      float* mnx = modesA + 12*((t+1)&1);
      if (tid<NIF) prs[tid]=ifc[tid];
      __syncthreads();
      if (tid<4) prs[256+tid]=softpl(prs[256+tid]);
      else if (tid==4) prs[324]=softpl(prs[324]);
      else if (tid>=64 && tid<128) prs[325+(tid-64)]=sigm(prs[325+(tid-64)]);
      else if (tid>=128 && tid<132) prs[453+(tid-128)]=sigm(prs[453+(tid-128)]);
      else if (tid==132) prs[457]=sigm(prs[457]);
      else if (tid==133) prs[458]=sigm(prs[458]);
      else if (tid>=136 && tid<140){
        int r=tid-136;
        float x0=prs[459+r*3],x1=prs[460+r*3],x2=prs[461+r*3];
        float mx=fmaxf(x0,fmaxf(x1,x2));
        float e0=expf(x0-mx),e1=expf(x1-mx),e2=expf(x2-mx),s=e0+e1+e2;
        prs[459+r*3]=e0/s; prs[460+r*3]=e1/s; prs[461+r*3]=e2/s;
        mnx[r*3+0]=e0/s; mnx[r*3+1]=e1/s; mnx[r*3+2]=e2/s;
      }
      {
        int wv=tid>>6, lane=tid&63;
        if (wv<4){
          float v = (wv==0)? prs[260+lane] : prs[(wv-1)*64+lane];
          v = red64s(v*v);
          if (lane==0) prs[471+wv]=sqrtf(v);
          if (wv==0){
            float u=prs[192+lane];
            u=red64s(u*u);
            if (lane==0) prs[475]=sqrtf(u);
          }
        }
      }
    }

    lbar(flg, b, g, 3u+(unsigned)t, tid);
  }

  // final barrier: partials_15 published during drain phase
  lbar(flg, b, g, 3u+NTT, tid);
  if (tid<256){
    const float* fb = ws + IFCF + ((NTT+1)&1)*PARF + b*BATF;
    float v=ldc(fb+B_RWP+(tid&15)*256+g*16+(tid>>4));
    v=red16s(v);
    if ((tid&15)==0) out[(size_t)(b*NTT+(NTT-1))*256 + g*16 + (tid>>4)] = v;
  }
}

extern "C" void kernel_launch(void* const* d_in, const int* in_sizes, int n_in,
                              void* d_out, int out_size, void* d_ws, size_t ws_size,
                              hipStream_t stream)
{
  const float* ctrl=(const float*)d_in[0];
  const float* wif =(const float*)d_in[1];
  const float* bif =(const float*)d_in[2];
  const float* mem0=(const float*)d_in[3];
  float* outp=(float*)d_out;
  unsigned* flg=(unsigned*)d_ws;
  float* wsf=(float*)((char*)d_ws+8192);

  hipMemsetAsync(d_ws, 0, 8192, stream);   // zero generation flags each launch

  void* args[]={(void*)&ctrl,(void*)&wif,(void*)&bif,(void*)&mem0,(void*)&outp,(void*)&wsf,(void*)&flg};
  hipError_t err = hipLaunchCooperativeKernel((void*)dnc_kernel, dim3(NBLK), dim3(BS), args, 0, stream);
  if (err != hipSuccess){
    hipLaunchKernelGGL(dnc_kernel, dim3(NBLK), dim3(BS), 0, stream,
                       ctrl, wif, bif, mem0, outp, wsf, flg);
  }
}